// Round 1
// baseline (249.767 us; speedup 1.0000x reference)
//
#include <hip/hip_runtime.h>
#include <stdint.h>

#define TT 16
#define BB 16
#define CC 256
#define HS 31
#define HT 15
#define OUTW 17
#define NCH 15                      // channels (flattened b,t,c) per block
#define NCHAN (BB*TT*CC)            // 65536
#define CORR_ELEMS ((size_t)NCHAN*OUTW*OUTW)

__device__ __forceinline__ unsigned short f2bf(float f) {
    unsigned u = __float_as_uint(f);
    u += 0x7fffu + ((u >> 16) & 1u);
    return (unsigned short)(u >> 16);
}
__device__ __forceinline__ float bflo(unsigned u) { return __uint_as_float(u << 16); }
__device__ __forceinline__ float bfhi(unsigned u) { return __uint_as_float(u & 0xffff0000u); }

__global__ __launch_bounds__(256, 4)
void corr_kernel(const float* __restrict__ s_f, const float* __restrict__ t_f,
                 float* __restrict__ corr)
{
    // s rows: stride 32 bf16, 16B-block swizzle by (y&3). w rows padded to 16.
    __shared__ __align__(16) unsigned short s_lds[NCH][HS][32];
    __shared__ __align__(16) unsigned short w_lds[NCH][HT][16];

    const int tid = threadIdx.x;
    const int ch_base = blockIdx.x * NCH;

    // ---- stage s tiles: f32 -> bf16, swizzled ----
    for (int j = 0; j < NCH; ++j) {
        int ch = ch_base + j;
        if (ch >= NCHAN) break;
        int bt = ch >> 8;       // / C
        int c  = ch & 255;
        int b  = bt >> 4;       // / T
        int t  = bt & 15;
        const float* src = s_f + (size_t)((t * BB + b) * CC + c) * (HS * HS);
        for (int e = tid; e < HS * HS; e += 256) {
            int y = e / 31;
            int x = e - y * 31;
            int col = (((x >> 3) ^ (y & 3)) << 3) | (x & 7);
            s_lds[j][y][col] = f2bf(src[e]);
        }
    }

    // ---- stage w: f32 -> bf16, rows padded to 16 (pad = 0) ----
    for (int idx = tid; idx < NCH * HT * 16; idx += 256) {
        int j   = idx / (HT * 16);
        int rem = idx - j * (HT * 16);
        int ky  = rem >> 4;
        int kx  = rem & 15;
        int ch  = ch_base + j;
        unsigned short h = 0;
        if (ch < NCHAN && kx < HT) {
            int bt = ch >> 8;
            int c  = ch & 255;
            int b  = bt >> 4;
            h = f2bf(t_f[(size_t)(b * CC + c) * (HT * HT) + ky * HT + kx]);
        }
        w_lds[j][ky][kx] = h;
    }

    __syncthreads();

    // ---- compute: thread = (c_sub, oy), owns one 17-wide output row ----
    const int c_sub = tid / OUTW;
    const int oy    = tid - c_sub * OUTW;
    const int ch    = ch_base + c_sub;
    if (c_sub >= NCH || ch >= NCHAN) return;

    float acc[OUTW];
#pragma unroll
    for (int m = 0; m < OUTW; ++m) acc[m] = 0.0f;

#pragma unroll 1
    for (int ky = 0; ky < HT; ++ky) {
        const int y = oy + ky;

        // w row -> 15 floats (wave-uniform broadcast reads)
        float wv[HT];
        {
            const uint4* wp = (const uint4*)(&w_lds[c_sub][ky][0]);
            uint4 w0 = wp[0];
            uint4 w1 = wp[1];
            unsigned wr[8] = {w0.x, w0.y, w0.z, w0.w, w1.x, w1.y, w1.z, w1.w};
#pragma unroll
            for (int i = 0; i < 7; ++i) {
                wv[2 * i]     = bflo(wr[i]);
                wv[2 * i + 1] = bfhi(wr[i]);
            }
            wv[14] = bflo(wr[7]);
        }

        // s row -> 31 floats (sv[31] unused)
        float sv[32];
        {
            const uint4* sp = (const uint4*)(&s_lds[c_sub][y][0]);
            const int sw = y & 3;
#pragma unroll
            for (int k = 0; k < 4; ++k) {
                uint4 d = sp[k ^ sw];
                sv[8 * k + 0] = bflo(d.x); sv[8 * k + 1] = bfhi(d.x);
                sv[8 * k + 2] = bflo(d.y); sv[8 * k + 3] = bfhi(d.y);
                sv[8 * k + 4] = bflo(d.z); sv[8 * k + 5] = bfhi(d.z);
                sv[8 * k + 6] = bflo(d.w); sv[8 * k + 7] = bfhi(d.w);
            }
        }

#pragma unroll
        for (int kx = 0; kx < HT; ++kx)
#pragma unroll
            for (int m = 0; m < OUTW; ++m)
                acc[m] = fmaf(sv[m + kx], wv[kx], acc[m]);
    }

    size_t base = (size_t)ch * (OUTW * OUTW) + (size_t)oy * OUTW;
#pragma unroll
    for (int m = 0; m < OUTW; ++m) corr[base + m] = acc[m];
}

__global__ void masks_kernel(const float* __restrict__ corr,
                             const int* __restrict__ pos,
                             float* __restrict__ masks)
{
    int gid = blockIdx.x * 256 + threadIdx.x;   // flattened (b*T+t)*C + c
    if (gid >= NCHAN) return;
    int bt = gid >> 8;
    int b  = bt >> 4;
    int t  = bt & 15;
    int p0 = pos[(b * TT + t) * 2 + 0];
    int p1 = pos[(b * TT + t) * 2 + 1];
    masks[gid] = corr[(size_t)gid * (OUTW * OUTW) + p0 * OUTW + p1];
}

extern "C" void kernel_launch(void* const* d_in, const int* in_sizes, int n_in,
                              void* d_out, int out_size, void* d_ws, size_t ws_size,
                              hipStream_t stream)
{
    const float* s_f = (const float*)d_in[0];
    const float* t_f = (const float*)d_in[1];
    const int*   pos = (const int*)d_in[2];
    float* corr  = (float*)d_out;
    float* masks = corr + CORR_ELEMS;

    int nblocks = (NCHAN + NCH - 1) / NCH;   // 4370
    corr_kernel<<<nblocks, 256, 0, stream>>>(s_f, t_f, corr);
    masks_kernel<<<NCHAN / 256, 256, 0, stream>>>(corr, pos, masks);
}

// Round 3
// 169.815 us; speedup vs baseline: 1.4708x; 1.4708x over previous
//
#include <hip/hip_runtime.h>
#include <stdint.h>

#define TT 16
#define BB 16
#define CC 256
#define HS 31
#define HT 15
#define OUTW 17
#define NCH 13                      // channels (flattened b,t,c) per block
#define NCHAN (BB*TT*CC)            // 65536
#define CORR_ELEMS ((size_t)NCHAN*OUTW*OUTW)

typedef _Float16 h2_t  __attribute__((ext_vector_type(2)));   // fdot2 operand type
typedef __fp16   fp162 __attribute__((ext_vector_type(2)));   // cvt_pkrtz result type

__device__ __forceinline__ unsigned packh2(float a, float b) {
    return __builtin_bit_cast(unsigned, __builtin_amdgcn_cvt_pkrtz(a, b));
}

__device__ __forceinline__ float fdot2f(unsigned a, unsigned b, float c) {
    return __builtin_amdgcn_fdot2(__builtin_bit_cast(h2_t, a),
                                  __builtin_bit_cast(h2_t, b), c, false);
}

// logical channel ch = (b*T + t)*C + c  ->  s_f index (t*B + b)*C + c
__device__ __forceinline__ int s_index(int ch) {
    int bt = ch >> 8;
    int c  = ch & 255;
    int b  = bt >> 4;
    int t  = bt & 15;
    return (t * BB + b) * CC + c;
}

__global__ __launch_bounds__(256, 4)
void corr_kernel(const float* __restrict__ s_f, const float* __restrict__ t_f,
                 float* __restrict__ corr)
{
    // s rows: 20 u32 (40 f16) = 80 B stride -> b128 slot = (5y+k)%8, conflict-free-ish.
    // only u32 cols 0..15 used (31 f16 + 1 zero pad).
    __shared__ __align__(16) unsigned s_u32[NCH][HS][20];
    __shared__ __align__(16) unsigned w_u32[NCH][HT][8];

    const int tid = threadIdx.x;
    const int ch_base = blockIdx.x * NCH;

    // ---- stage s: f32 pairs -> packed f16 ----
    {
        const int jcol = tid & 15;       // u32 col
        const int r0   = tid >> 4;       // row 0..15
        const int x0   = 2 * jcol;
        for (int j = 0; j < NCH; ++j) {
            int ch = ch_base + j;
            if (ch >= NCHAN) break;
            const float* src = s_f + (size_t)s_index(ch) * (HS * HS);
            {
                float a = src[r0 * HS + x0];
                float b = (x0 + 1 < HS) ? src[r0 * HS + x0 + 1] : 0.0f;
                s_u32[j][r0][jcol] = packh2(a, b);
            }
            int r1 = r0 + 16;
            if (r1 < HS) {
                float a = src[r1 * HS + x0];
                float b = (x0 + 1 < HS) ? src[r1 * HS + x0 + 1] : 0.0f;
                s_u32[j][r1][jcol] = packh2(a, b);
            }
        }
    }

    // ---- stage w: 15 f16 per row packed into 8 u32 (last pair hi = 0) ----
    for (int idx = tid; idx < NCH * HT * 8; idx += 256) {
        int j   = idx / (HT * 8);
        int rem = idx - j * (HT * 8);
        int ky  = rem >> 3;
        int p   = rem & 7;
        int ch  = ch_base + j;
        unsigned v = 0;
        if (ch < NCHAN) {
            int bt = ch >> 8;
            int c  = ch & 255;
            int b  = bt >> 4;
            const float* wsrc = t_f + (size_t)(b * CC + c) * (HT * HT) + ky * HT;
            float a  = wsrc[2 * p];
            float bb = (2 * p + 1 < HT) ? wsrc[2 * p + 1] : 0.0f;
            v = packh2(a, bb);
        }
        w_u32[j][ky][p] = v;
    }

    __syncthreads();

    // ---- compute: thread = (c_sub, oy) owns one 17-wide output row ----
    const int c_sub = tid / OUTW;
    const int oy    = tid - c_sub * OUTW;
    const int ch    = ch_base + c_sub;
    if (c_sub >= NCH || ch >= NCHAN) return;

    float acc[OUTW];
#pragma unroll
    for (int m = 0; m < OUTW; ++m) acc[m] = 0.0f;

#pragma unroll 1
    for (int ky = 0; ky < HT; ++ky) {
        const int y = oy + ky;

        // s row: 16 packed pairs (aligned)
        unsigned sp[16];
        {
            const uint4* rp = (const uint4*)(&s_u32[c_sub][y][0]);
#pragma unroll
            for (int k = 0; k < 4; ++k) {
                uint4 d = rp[k];
                sp[4 * k + 0] = d.x; sp[4 * k + 1] = d.y;
                sp[4 * k + 2] = d.z; sp[4 * k + 3] = d.w;
            }
        }
        // odd-offset pairs: so[j] = (s[2j+1], s[2j+2])
        unsigned so[15];
#pragma unroll
        for (int j = 0; j < 15; ++j)
            so[j] = __builtin_amdgcn_alignbit(sp[j + 1], sp[j], 16);

        // w row: 8 packed pairs (wave-uniform broadcast)
        unsigned wp[8];
        {
            const uint4* rp = (const uint4*)(&w_u32[c_sub][ky][0]);
            uint4 w0 = rp[0], w1 = rp[1];
            wp[0] = w0.x; wp[1] = w0.y; wp[2] = w0.z; wp[3] = w0.w;
            wp[4] = w1.x; wp[5] = w1.y; wp[6] = w1.z; wp[7] = w1.w;
        }

        // even output cols m = 2e
#pragma unroll
        for (int e = 0; e < 9; ++e)
#pragma unroll
            for (int j = 0; j < 8; ++j)
                acc[2 * e] = fdot2f(sp[e + j], wp[j], acc[2 * e]);
        // odd output cols m = 2o+1
#pragma unroll
        for (int o = 0; o < 8; ++o)
#pragma unroll
            for (int j = 0; j < 8; ++j)
                acc[2 * o + 1] = fdot2f(so[o + j], wp[j], acc[2 * o + 1]);
    }

    size_t base = (size_t)ch * (OUTW * OUTW) + (size_t)oy * OUTW;
#pragma unroll
    for (int m = 0; m < OUTW; ++m) corr[base + m] = acc[m];
}

__global__ void masks_kernel(const float* __restrict__ corr,
                             const int* __restrict__ pos,
                             float* __restrict__ masks)
{
    int gid = blockIdx.x * 256 + threadIdx.x;   // flattened (b*T+t)*C + c
    if (gid >= NCHAN) return;
    int bt = gid >> 8;
    int b  = bt >> 4;
    int t  = bt & 15;
    int p0 = pos[(b * TT + t) * 2 + 0];
    int p1 = pos[(b * TT + t) * 2 + 1];
    masks[gid] = corr[(size_t)gid * (OUTW * OUTW) + p0 * OUTW + p1];
}

extern "C" void kernel_launch(void* const* d_in, const int* in_sizes, int n_in,
                              void* d_out, int out_size, void* d_ws, size_t ws_size,
                              hipStream_t stream)
{
    const float* s_f = (const float*)d_in[0];
    const float* t_f = (const float*)d_in[1];
    const int*   pos = (const int*)d_in[2];
    float* corr  = (float*)d_out;
    float* masks = corr + CORR_ELEMS;

    int nblocks = (NCHAN + NCH - 1) / NCH;   // 5042
    corr_kernel<<<nblocks, 256, 0, stream>>>(s_f, t_f, corr);
    masks_kernel<<<NCHAN / 256, 256, 0, stream>>>(corr, pos, masks);
}

// Round 4
// 151.010 us; speedup vs baseline: 1.6540x; 1.1245x over previous
//
#include <hip/hip_runtime.h>
#include <stdint.h>

#define TT 16
#define BB 16
#define CC 256
#define HS 31
#define HT 15
#define OUTW 17
#define NCH 15                      // channels (flattened b,t,c) per block
#define NCHAN (BB*TT*CC)            // 65536
#define CORR_ELEMS ((size_t)NCHAN*OUTW*OUTW)

typedef _Float16 h2_t __attribute__((ext_vector_type(2)));

__device__ __forceinline__ unsigned packh2(float a, float b) {
    return __builtin_bit_cast(unsigned, __builtin_amdgcn_cvt_pkrtz(a, b));
}
__device__ __forceinline__ float fdot2f(unsigned a, unsigned b, float c) {
    return __builtin_amdgcn_fdot2(__builtin_bit_cast(h2_t, a),
                                  __builtin_bit_cast(h2_t, b), c, false);
}

// logical channel ch = (b*T + t)*C + c  ->  s_f index (t*B + b)*C + c
__device__ __forceinline__ int s_index(int ch) {
    int bt = ch >> 8, c = ch & 255;
    int b = bt >> 4, t = bt & 15;
    return (t * BB + b) * CC + c;
}

__global__ __launch_bounds__(256, 4)
void corr_kernel(const float* __restrict__ s_f, const float* __restrict__ t_f,
                 float* __restrict__ corr)
{
    // s: [NCH][31][16 u32] (64B row stride). u32 col c of row y stored at
    //    col ((c>>2 ^ (y&3))<<2) | (c&3)  (b128-unit XOR swizzle).
    //    31 f16 per row + 1 zero pad in the hi half of col 15.
    // w: [NCH][15][8 u32] = 15 f16 + zero pad.
    __shared__ __align__(16) unsigned s_u32[NCH][HS][16];
    __shared__ __align__(16) unsigned w_u32[NCH][HT][8];

    const int tid = threadIdx.x;
    const int ch_base = blockIdx.x * NCH;

    // ---- stage s: pipelined, clamp tail (no break) ----
    {
        const int jcol = tid & 15;       // pair-column 0..15
        const int r0   = tid >> 4;       // row 0..15
        const int x0   = 2 * jcol;
        const bool hasb  = (jcol < 15);
        const int  r1    = r0 + 16;
        const bool hasr1 = (r1 < HS);    // tid < 240
        const int c0 = (((jcol >> 2) ^ (r0 & 3)) << 2) | (jcol & 3);
        const int c1 = (((jcol >> 2) ^ (r1 & 3)) << 2) | (jcol & 3);
#pragma unroll
        for (int j = 0; j < NCH; ++j) {
            int ch = ch_base + j; if (ch >= NCHAN) ch = NCHAN - 1;
            const float* src = s_f + (size_t)s_index(ch) * (HS * HS);
            float a0 = src[r0 * HS + x0];
            float b0 = hasb ? src[r0 * HS + x0 + 1] : 0.0f;
            float a1 = hasr1 ? src[r1 * HS + x0] : 0.0f;
            float b1 = (hasr1 && hasb) ? src[r1 * HS + x0 + 1] : 0.0f;
            s_u32[j][r0][c0] = packh2(a0, b0);
            if (hasr1) s_u32[j][r1][c1] = packh2(a1, b1);
        }
    }

    // ---- stage w ----
    {
        const int j    = tid >> 4;       // channel 0..15 (15 skipped)
        const int lane = tid & 15;
        if (j < NCH) {
            int ch = ch_base + j; if (ch >= NCHAN) ch = NCHAN - 1;
            int bt = ch >> 8, c = ch & 255, b = bt >> 4;
            const float* wsrc = t_f + (size_t)(b * CC + c) * (HT * HT);
#pragma unroll
            for (int q0 = 0; q0 < 8; ++q0) {
                int q = q0 * 16 + lane;
                if (q < HT * 8) {
                    int ky = q >> 3, p = q & 7;
                    float a  = wsrc[ky * HT + 2 * p];
                    float bb = (p < 7) ? wsrc[ky * HT + 2 * p + 1] : 0.0f;
                    w_u32[j][ky][p] = packh2(a, bb);
                }
            }
        }
    }

    __syncthreads();

    // ---- compute: thread = (c_sub, oy) owns one 17-wide output row ----
    const int c_sub = tid / OUTW;
    const int oy    = tid - c_sub * OUTW;
    const int ch    = ch_base + c_sub;
    if (c_sub >= NCH || ch >= NCHAN) return;

    float acc[OUTW];
#pragma unroll
    for (int m = 0; m < OUTW; ++m) acc[m] = 0.0f;

#pragma unroll 1
    for (int ky = 0; ky < HT; ++ky) {
        const int y  = oy + ky;
        const int sw = y & 3;

        // w row: wp[j] = (w[2j], w[2j+1]) (w[15]=0); wo[r] = (w[2r-1], w[2r]) (w[-1]=0)
        unsigned wp[8], wo[8];
        {
            const uint4* rp = (const uint4*)(&w_u32[c_sub][ky][0]);
            uint4 w0 = rp[0], w1 = rp[1];
            wp[0] = w0.x; wp[1] = w0.y; wp[2] = w0.z; wp[3] = w0.w;
            wp[4] = w1.x; wp[5] = w1.y; wp[6] = w1.z; wp[7] = w1.w;
            wo[0] = __builtin_amdgcn_alignbit(wp[0], 0u, 16);
#pragma unroll
            for (int r = 1; r < 8; ++r)
                wo[r] = __builtin_amdgcn_alignbit(wp[r], wp[r - 1], 16);
        }

        // stream s row in b128 chunks; sp[p] = (s[2p], s[2p+1])
        const uint4* srow = (const uint4*)(&s_u32[c_sub][y][0]);
#pragma unroll
        for (int u = 0; u < 4; ++u) {
            uint4 d = srow[u ^ sw];
            unsigned spc[4] = {d.x, d.y, d.z, d.w};
#pragma unroll
            for (int q = 0; q < 4; ++q) {
                const int p = 4 * u + q;
                // even outputs m = 2*(p-j): acc += dot2(sp[p], wp[j])
#pragma unroll
                for (int j = (p > 8 ? p - 8 : 0); j <= (p < 7 ? p : 7); ++j)
                    acc[2 * (p - j)] = fdot2f(spc[q], wp[j], acc[2 * (p - j)]);
                // odd outputs m = 2*(p-r)+1: acc += dot2(sp[p], wo[r])
#pragma unroll
                for (int r = (p > 7 ? p - 7 : 0); r <= (p < 7 ? p : 7); ++r)
                    acc[2 * (p - r) + 1] = fdot2f(spc[q], wo[r], acc[2 * (p - r) + 1]);
            }
        }
    }

    size_t base = (size_t)ch * (OUTW * OUTW) + (size_t)oy * OUTW;
#pragma unroll
    for (int m = 0; m < OUTW; ++m) corr[base + m] = acc[m];
}

__global__ void masks_kernel(const float* __restrict__ corr,
                             const int* __restrict__ pos,
                             float* __restrict__ masks)
{
    int gid = blockIdx.x * 256 + threadIdx.x;   // flattened (b*T+t)*C + c
    if (gid >= NCHAN) return;
    int bt = gid >> 8;
    int b  = bt >> 4;
    int t  = bt & 15;
    int p0 = pos[(b * TT + t) * 2 + 0];
    int p1 = pos[(b * TT + t) * 2 + 1];
    masks[gid] = corr[(size_t)gid * (OUTW * OUTW) + p0 * OUTW + p1];
}

extern "C" void kernel_launch(void* const* d_in, const int* in_sizes, int n_in,
                              void* d_out, int out_size, void* d_ws, size_t ws_size,
                              hipStream_t stream)
{
    const float* s_f = (const float*)d_in[0];
    const float* t_f = (const float*)d_in[1];
    const int*   pos = (const int*)d_in[2];
    float* corr  = (float*)d_out;
    float* masks = corr + CORR_ELEMS;

    int nblocks = (NCHAN + NCH - 1) / NCH;   // 4370
    corr_kernel<<<nblocks, 256, 0, stream>>>(s_f, t_f, corr);
    masks_kernel<<<NCHAN / 256, 256, 0, stream>>>(corr, pos, masks);
}